// Round 7
// baseline (146.335 us; speedup 1.0000x reference)
//
#include <hip/hip_runtime.h>

// TV loss via exact spatial-domain identity of the FFT pipeline:
//   gx[y,x] = in[y,x] - in[y,(x+1)%W]
//   gy[y,x] = in[y,x] - in[(y+1)%H,x]
//   result  = sum(sqrt(gx^2 + gy^2)) / (B*C*H*W)
// Shapes fixed: B=32, C=3, H=512, W=512 (fp32).
//
// Structure: each block owns a 16-row slice of one plane. Staging uses
// __builtin_amdgcn_global_load_lds (16 B direct-to-LDS DMA, no dest VGPRs)
// so each wave keeps all 9 staging loads in flight — this tests whether the
// ~2.1 TB/s wall seen in rounds 1-6 was a VGPR-bound MLP limit.
// Tile = 17 rows x 512 floats (16 compute + 1 halo) = 34,816 B LDS ->
// 4 blocks/CU. Compute: wave w pipelines rows 4w..4w+4 from LDS via
// ds_read_b128 (register-carry reuse), shfl for the x-seam and x-wrap.

#define DIM_H 512
#define DIM_W 512
#define PLANES 96                        // B*C
#define TOTAL (PLANES * DIM_H * DIM_W)   // 25165824
#define W4 128                           // float4 per row
#define ROWS 16                          // compute rows per block
#define SLICES (DIM_H / ROWS)            // 32
#define NTHREADS 256
#define NBLOCKS (PLANES * SLICES)        // 3072
#define TILE_F4 ((ROWS + 1) * W4)        // 2176 float4 in LDS

__global__ __launch_bounds__(NTHREADS, 4) void tv_partial(const float* __restrict__ in,
                                                          float* __restrict__ partial) {
    __shared__ float4 tile[TILE_F4];     // 34,816 B
    __shared__ float smem[NTHREADS / 64];

    const int t    = threadIdx.x;
    const int lane = t & 63;
    const int w    = t >> 6;
    const int p    = blockIdx.x >> 5;            // plane
    const int k    = blockIdx.x & (SLICES - 1);  // slice

    // Global float4 base of this block's 16-row tile.
    const int gbase = (p << 16) + (k << 11);     // k*16 rows * 128 f4
    // Halo row: global row (16k+16) % 512.
    const int hbase = (k == SLICES - 1) ? (p << 16) : (gbase + ROWS * W4);

    const float4* __restrict__ in4 = (const float4*)in;

    // ---- Stage: 8 direct-to-LDS loads per thread + halo (waves 0,1) ----
    // LDS dest must be wave-uniform base + lane*16: index = (j*256 + w*64) + lane.
    #pragma unroll
    for (int j = 0; j < 8; ++j) {
        __builtin_amdgcn_global_load_lds(
            (const __attribute__((address_space(1))) void*)(in4 + gbase + j * 256 + t),
            (__attribute__((address_space(3))) void*)(tile + j * 256 + w * 64),
            16, 0, 0);
    }
    if (w < 2) {  // 128 halo float4 by waves 0 and 1 (wave-uniform branch)
        __builtin_amdgcn_global_load_lds(
            (const __attribute__((address_space(1))) void*)(in4 + hbase + w * 64 + lane),
            (__attribute__((address_space(3))) void*)(tile + 2048 + w * 64),
            16, 0, 0);
    }
    __syncthreads();   // compiler inserts vmcnt(0) drain before barrier

    // ---- Compute: wave w handles rows 4w..4w+3 (reads rows 4w..4w+4) ----
    const int src = (lane + 1) & 63;
    const bool last = (lane == 63);
    float s = 0.0f;

    int r0 = w << 2;
    float4 A = tile[(r0 << 7) + lane];
    float4 B = tile[(r0 << 7) + 64 + lane];

#define TV_ROW(A_, B_, DA_, DB_)                                                 \
    do {                                                                         \
        float n0 = __shfl((A_).x, src, 64);                                      \
        float n1 = __shfl((B_).x, src, 64);                                      \
        float e0 = last ? n1 : n0; /* right of A.w (seam at float 256) */        \
        float e1 = last ? n0 : n1; /* right of B.w (x-wrap 511->0) */            \
        float tt;                                                                \
        tt = (A_).x - (A_).y; s += sqrtf(tt*tt + ((A_).x-(DA_).x)*((A_).x-(DA_).x)); \
        tt = (A_).y - (A_).z; s += sqrtf(tt*tt + ((A_).y-(DA_).y)*((A_).y-(DA_).y)); \
        tt = (A_).z - (A_).w; s += sqrtf(tt*tt + ((A_).z-(DA_).z)*((A_).z-(DA_).z)); \
        tt = (A_).w - e0;     s += sqrtf(tt*tt + ((A_).w-(DA_).w)*((A_).w-(DA_).w)); \
        tt = (B_).x - (B_).y; s += sqrtf(tt*tt + ((B_).x-(DB_).x)*((B_).x-(DB_).x)); \
        tt = (B_).y - (B_).z; s += sqrtf(tt*tt + ((B_).y-(DB_).y)*((B_).y-(DB_).y)); \
        tt = (B_).z - (B_).w; s += sqrtf(tt*tt + ((B_).z-(DB_).z)*((B_).z-(DB_).z)); \
        tt = (B_).w - e1;     s += sqrtf(tt*tt + ((B_).w-(DB_).w)*((B_).w-(DB_).w)); \
    } while (0)

    #pragma unroll
    for (int j = 1; j <= 4; ++j) {
        int rn = r0 + j;
        float4 DA = tile[(rn << 7) + lane];
        float4 DB = tile[(rn << 7) + 64 + lane];
        TV_ROW(A, B, DA, DB);
        A = DA;
        B = DB;
    }
#undef TV_ROW

    // ---- Reduce ----
    #pragma unroll
    for (int off = 32; off > 0; off >>= 1)
        s += __shfl_down(s, off, 64);

    if (lane == 0) smem[w] = s;
    __syncthreads();
    if (t == 0)
        partial[blockIdx.x] = smem[0] + smem[1] + smem[2] + smem[3];
}

__global__ __launch_bounds__(256) void tv_final(const float* __restrict__ partial,
                                                float* __restrict__ out) {
    float s = 0.0f;
    for (int i = threadIdx.x; i < NBLOCKS; i += 256)
        s += partial[i];

    #pragma unroll
    for (int off = 32; off > 0; off >>= 1)
        s += __shfl_down(s, off, 64);

    __shared__ float smem[4];
    int lane = threadIdx.x & 63;
    int wave = threadIdx.x >> 6;
    if (lane == 0) smem[wave] = s;
    __syncthreads();
    if (threadIdx.x == 0)
        out[0] = (smem[0] + smem[1] + smem[2] + smem[3]) * (1.0f / (float)TOTAL);
}

extern "C" void kernel_launch(void* const* d_in, const int* in_sizes, int n_in,
                              void* d_out, int out_size, void* d_ws, size_t ws_size,
                              hipStream_t stream) {
    const float* in = (const float*)d_in[0];
    float* out = (float*)d_out;
    float* partial = (float*)d_ws;  // NBLOCKS floats of scratch

    tv_partial<<<NBLOCKS, NTHREADS, 0, stream>>>(in, partial);
    tv_final<<<1, 256, 0, stream>>>(partial, out);
}